// Round 2
// 162.371 us; speedup vs baseline: 1.0371x; 1.0371x over previous
//
#include <hip/hip_runtime.h>
#include <hip/hip_bf16.h>

// Problem constants
#define BB 2
#define LL 2048
#define DD 512
#define HH 8
#define HDM 64
#define SCALE 0.022097086912079608f    // 1/sqrt(2048)
#define QSCALE 0.03187935766f          // SCALE * log2(e)  (exp2-domain softmax)

typedef __hip_bfloat16 bf16;
typedef unsigned short u16;
typedef __attribute__((ext_vector_type(8))) short short8v;   // 8 bf16 (4 VGPRs)
typedef __attribute__((ext_vector_type(4))) float float4v;   // 4 fp32 acc

// Input element counts
#define XN  2097152    // 2*2048*512
#define WN  2359296    // 1536*512*3
#define BN  1536
#define FWN 262144     // 512*512
#define FBN 512

__device__ __forceinline__ float b2f(u16 u) {
    return __uint_as_float(((unsigned int)u) << 16);
}
__device__ __forceinline__ u16 f2u(float f) {
    bf16 h = __float2bfloat16(f);
    u16 r;
    __builtin_memcpy(&r, &h, 2);
    return r;
}
__device__ __forceinline__ uint4 pack8(const float* f) {
    uint4 p;
    p.x = (unsigned)f2u(f[0]) | ((unsigned)f2u(f[1]) << 16);
    p.y = (unsigned)f2u(f[2]) | ((unsigned)f2u(f[3]) << 16);
    p.z = (unsigned)f2u(f[4]) | ((unsigned)f2u(f[5]) << 16);
    p.w = (unsigned)f2u(f[6]) | ((unsigned)f2u(f[7]) << 16);
    return p;
}

// async 16-B global -> LDS copy (lds dest = wave-uniform base + lane*16)
__device__ __forceinline__ void gld_lds16(const u16* g, u16* l) {
    __builtin_amdgcn_global_load_lds(
        (const __attribute__((address_space(1))) unsigned int*)g,
        (__attribute__((address_space(3))) unsigned int*)l, 16, 0, 0);
}

// dtype detect (f32 vs bf16 inputs), computed locally per wave — all waves
// read the same first 256 half-words of raw x, so result is uniform and
// deterministic across all blocks/kernels.
__device__ __forceinline__ int detect_flag(const u16* __restrict__ xraw) {
    int bad = 0;
    int lane = threadIdx.x & 63;
    for (int i = lane; i < 256; i += 64) {
        float v = b2f(xraw[i]);
        if (!(fabsf(v) < 100.f)) bad = 1;   // catches NaN too
    }
    return (__ballot(bad) != 0ull) ? 1 : 0;
}

__device__ __forceinline__ void conv8(const void* src, u16* dst, size_t i, int flag) {
    if (flag) {
        const float* s = (const float*)src;
        float f[8];
        float4 a = *(const float4*)(s + i);
        float4 b = *(const float4*)(s + i + 4);
        f[0] = a.x; f[1] = a.y; f[2] = a.z; f[3] = a.w;
        f[4] = b.x; f[5] = b.y; f[6] = b.z; f[7] = b.w;
        *(uint4*)(dst + i) = pack8(f);
    } else {
        *(uint4*)(dst + i) = *(const uint4*)((const u16*)src + i);
    }
}

// -------------------------------------------------------------------------
// Kernel 0: unified prep — one launch, block-range branch:
//   [0,1024)    : x -> zero-guard-padded xp[B][2050][512] (+ guard rows)
//   [1024,2176) : cnn_w canonicalize + transpose [o][i][k]->[o][k*512+i]
//   [2176,2305) : cnn_b + fc_w + fc_b converts
// -------------------------------------------------------------------------
__global__ __launch_bounds__(256) void prep_kernel(
    const void* __restrict__ xsrc, const void* __restrict__ wsrc,
    const void* __restrict__ bsrc, const void* __restrict__ fwsrc,
    const void* __restrict__ fbsrc,
    u16* __restrict__ xp, u16* __restrict__ wt,
    u16* __restrict__ bc, u16* __restrict__ fwc, u16* __restrict__ fbc)
{
    const int flag = detect_flag((const u16*)xsrc);
    const int bid = blockIdx.x;

    if (bid < 1024) {
        // ---- xpad ----
        int idx = bid * 256 + threadIdx.x;           // octet id, < 2*2048*64
        if (idx < 256) {
            int b2  = idx >> 7;
            int r2  = (idx >> 6) & 1;
            int c82 = (idx & 63) * 8;
            size_t off = ((size_t)(b2 * 2050 + (r2 ? 2049 : 0))) * 512 + c82;
            uint4 z = {0u, 0u, 0u, 0u};
            *(uint4*)(xp + off) = z;
        }
        int b   = idx / (LL * 64);
        int rem = idx - b * (LL * 64);
        int l   = rem >> 6;
        int c8  = (rem & 63) * 8;
        size_t si = ((size_t)(b * LL + l)) * 512 + c8;
        size_t di = ((size_t)(b * 2050 + l + 1)) * 512 + c8;
        if (flag) {
            const float* s = (const float*)xsrc;
            float f[8];
            float4 a = *(const float4*)(s + si);
            float4 bq = *(const float4*)(s + si + 4);
            f[0] = a.x; f[1] = a.y; f[2] = a.z; f[3] = a.w;
            f[4] = bq.x; f[5] = bq.y; f[6] = bq.z; f[7] = bq.w;
            *(uint4*)(xp + di) = pack8(f);
        } else {
            *(uint4*)(xp + di) = *(const uint4*)((const u16*)xsrc + si);
        }
    } else if (bid < 2176) {
        // ---- convw ----
        int idx = (bid - 1024) * 256 + threadIdx.x;  // < 1536*3*64
        int i8  = idx & 63;
        int rem = idx >> 6;
        int k   = rem % 3;
        int o   = rem / 3;
        float f[8];
        if (flag) {
            const float* s = (const float*)wsrc;
#pragma unroll
            for (int j = 0; j < 8; ++j) f[j] = s[(size_t)o * 1536 + (i8 * 8 + j) * 3 + k];
        } else {
            const u16* s = (const u16*)wsrc;
#pragma unroll
            for (int j = 0; j < 8; ++j) f[j] = b2f(s[(size_t)o * 1536 + (i8 * 8 + j) * 3 + k]);
        }
        *(uint4*)(wt + (size_t)o * 1536 + k * 512 + i8 * 8) = pack8(f);
    } else {
        // ---- small converts ----
        int o = (bid - 2176) * 256 + threadIdx.x;    // octet id
        if (o < BN / 8) {
            conv8(bsrc, bc, (size_t)o * 8, flag);
        } else if (o < BN / 8 + FWN / 8) {
            conv8(fwsrc, fwc, (size_t)(o - BN / 8) * 8, flag);
        } else if (o < BN / 8 + FWN / 8 + FBN / 8) {
            conv8(fbsrc, fbc, (size_t)(o - BN / 8 - FWN / 8) * 8, flag);
        }
    }
}

// -------------------------------------------------------------------------
// Kernel 1: conv GEMM — R12-verified form: 128x128 tiles, 384 blocks,
// m97-style K-loop (global_load_lds 16B, XOR bank swizzle, 1 barrier/chunk),
// LDS-transpose epilogue (coalesced qkbuf/vbuf writes), QSCALE fold into Q.
// V-columns are written in the tile-interleaved key order n(w)=8*((w>>2)&3)
// +4*(w>>4)+(w&3) within each 32-key group so the attention kernel's
// register-resident P^T feeds PV MFMAs with zero cross-lane exchange.
// -------------------------------------------------------------------------
__global__ __launch_bounds__(256) void conv_mfma_kernel(
    const u16* __restrict__ xp,     // [B][2050][512] padded bf16
    const u16* __restrict__ wt,     // [1536][1536] = [o][k*512+i]
    const u16* __restrict__ bias,   // [1536]
    u16* __restrict__ qkbuf,        // [B*H][2][L][64]
    u16* __restrict__ vbuf)         // [B*H][64][L] (key-permuted, see above)
{
    __shared__ u16 smem[32768];     // 65536 B
    u16* Asb = smem;                // [2][128][64] unpadded, swizzled
    u16* Bsb = smem + 2 * 128 * 64; // [2][128][64] unpadded, swizzled
#define OTS 140
    u16* OT  = smem;                // [128][140] aliased after final sync

    const int blk = blockIdx.x;          // rt*12 + ct
    const int rt = blk / 12;
    const int ct = blk - rt * 12;
    const int b  = rt >> 4;
    const int l0 = (rt & 15) * 128;
    const int tid  = threadIdx.x;
    const int wave = tid >> 6;
    const int lane = tid & 63;
    const int quad = lane >> 4;
    const int l16  = lane & 15;
    const int e7   = l16 & 7;
    const int wx = wave & 1;             // n half
    const int wy = wave >> 1;            // m half

    float4v acc[4][4];
#pragma unroll
    for (int mt = 0; mt < 4; ++mt)
#pragma unroll
        for (int nt = 0; nt < 4; ++nt) acc[mt][nt] = (float4v){0.f, 0.f, 0.f, 0.f};

    const int rowW = wave * 32;
    const int lrow = lane >> 3;          // 0..7
    const int g8   = (((lane & 7) ^ lrow)) * 8;
    auto stage = [&](int kc, int buf) {
        const int slab = kc >> 3;                // conv tap k (0..2)
        const int i0   = (kc & 7) * 64;          // input-channel slice
        const u16* ga = xp + ((size_t)(b * 2050 + l0 + rowW + slab + lrow)) * 512 + i0 + g8;
        const u16* gb = wt + ((size_t)(ct * 128 + rowW + lrow)) * 1536 + kc * 64 + g8;
        u16* la = Asb + (size_t)(buf * 128 + rowW) * 64;
        u16* lb = Bsb + (size_t)(buf * 128 + rowW) * 64;
#pragma unroll
        for (int j = 0; j < 4; ++j) {
            gld_lds16(ga + (size_t)(j * 8) * 512,  la + (j * 8) * 64);
            gld_lds16(gb + (size_t)(j * 8) * 1536, lb + (j * 8) * 64);
        }
    };

    stage(0, 0);

    for (int kc = 0; kc < 24; ++kc) {
        const int cur = kc & 1;
        __syncthreads();   // drains vmcnt -> chunk kc staged; prev reads done

        if (kc < 23) stage(kc + 1, 1 - cur);

#pragma unroll
        for (int half = 0; half < 2; ++half) {
            const int p = ((half * 4 + quad) ^ e7) * 8;   // swizzled chunk
            short8v aF[4], bF[4];
#pragma unroll
            for (int mt = 0; mt < 4; ++mt)
                aF[mt] = *(const short8v*)&Asb[(size_t)(cur * 128 + wy * 64 + mt * 16 + l16) * 64 + p];
#pragma unroll
            for (int nt = 0; nt < 4; ++nt)
                bF[nt] = *(const short8v*)&Bsb[(size_t)(cur * 128 + wx * 64 + nt * 16 + l16) * 64 + p];
#pragma unroll
            for (int mt = 0; mt < 4; ++mt)
#pragma unroll
                for (int nt = 0; nt < 4; ++nt)
                    acc[mt][nt] = __builtin_amdgcn_mfma_f32_16x16x32_bf16(
                        aF[mt], bF[nt], acc[mt][nt], 0, 0, 0);
        }
    }

    // ---- epilogue stage 1: bias+swish(+QSCALE) in regs -> OT [128 l][128 o]
    __syncthreads();   // all LDS tile reads done; safe to alias as OT
    {
        const int tloc = (ct * 2 + wx) % 3;   // t for this wave's col group
#pragma unroll
        for (int nt = 0; nt < 4; ++nt) {
            int oc = wx * 64 + nt * 16 + l16;           // tile-local col
            float bb = b2f(bias[ct * 128 + oc]);
#pragma unroll
            for (int mt = 0; mt < 4; ++mt)
#pragma unroll
                for (int r = 0; r < 4; ++r) {
                    int lr = wy * 64 + mt * 16 + quad * 4 + r;   // tile-local row
                    float y = acc[mt][nt][r] + bb;
                    y = y / (1.f + __expf(-y));                  // swish
                    if (tloc == 0) y *= QSCALE;                  // fold scale*log2e into Q
                    OT[lr * OTS + oc] = f2u(y);
                }
        }
    }
    __syncthreads();

    // ---- epilogue stage 2: coalesced write-out per 64-col group
#pragma unroll
    for (int g = 0; g < 2; ++g) {
        int a  = ct * 2 + g;        // 64-col group index (0..23)
        int t  = a % 3;
        int bh = b * HH + a / 3;
        if (t != 2) {
            u16* base = qkbuf + ((size_t)((bh * 2 + t) * LL + l0)) * HDM;
#pragma unroll
            for (int it = 0; it < 4; ++it) {
                int idx = it * 256 + tid;       // 0..1023
                int l   = idx >> 3;             // 0..127
                int d8  = (idx & 7) * 8;        // 0..56
                uint4 val = *(const uint4*)&OT[l * OTS + g * 64 + d8];
                *(uint4*)(base + (size_t)l * HDM + d8) = val;
            }
        } else {
            u16* base = vbuf + ((size_t)(bh * HDM)) * LL + l0;
#pragma unroll
            for (int it = 0; it < 4; ++it) {
                int idx = it * 256 + tid;       // 0..1023
                int dd  = idx >> 4;             // 0..63
                int p   = idx & 15;             // 8-col group within 128 tile
                int l8  = p * 8;
                u16 tmp[8];
#pragma unroll
                for (int j = 0; j < 8; ++j) tmp[j] = OT[(l8 + j) * OTS + g * 64 + dd];
                // tile-interleaved key permute within each 32-key group:
                // orig w -> n = 8*((w>>2)&3) + 4*(w>>4) + (w&3)
                int a32 = p >> 2;                // 32-key group
                int pb_ = p & 3;
                int q2  = (2 * pb_) & 3;
                int h2  = pb_ >> 1;
                int n0  = 32 * a32 + 8 * q2 + 4 * h2;   // j=0..3 run
                uint2 v0, v1;
                v0.x = (unsigned)tmp[0] | ((unsigned)tmp[1] << 16);
                v0.y = (unsigned)tmp[2] | ((unsigned)tmp[3] << 16);
                v1.x = (unsigned)tmp[4] | ((unsigned)tmp[5] << 16);
                v1.y = (unsigned)tmp[6] | ((unsigned)tmp[7] << 16);
                *(uint2*)(base + (size_t)dd * LL + n0)     = v0;   // j=0..3
                *(uint2*)(base + (size_t)dd * LL + n0 + 8) = v1;   // j=4..7
            }
        }
    }
#undef OTS
}

// -------------------------------------------------------------------------
// Kernel 2: MFMA flash attention per (b,h) — register-resident P^T form:
// swapped QK^T (S^T = mfma(K,Q)) puts query in l16, keys in rows; exp2'd
// P packs straight into PV B-frags (V pre-permuted at conv output), so the
// P LDS round-trip (32 ds_write_b16 + 4 ds_read_b128 per wave-chunk) and
// its in-wave write->read latency chain are gone. Row sums via ones-row
// A-operand MFMA; output computed transposed (row=d, col=query).
// -------------------------------------------------------------------------
__global__ __launch_bounds__(256) void attn_mfma_kernel(
    const u16* __restrict__ qk,    // [B*H][2][L][64]
    const u16* __restrict__ v,     // [B*H][64][L] key-permuted
    u16* __restrict__ newv)        // [B][L][512]
{
    __shared__ u16 kts[2][128][64];  // [buf][m][d] swizzled
    __shared__ u16 vts[2][64][128];  // [buf][d][m] swizzled (m = permuted key)

    const int blkid = blockIdx.x;        // bh*32 + wchunk
    const int bh = blkid >> 5;
    const int wc = blkid & 31;
    const int b  = bh >> 3;
    const int h  = bh & 7;
    const int tid  = threadIdx.x;
    const int wave = tid >> 6;
    const int lane = tid & 63;
    const int quad = lane >> 4;
    const int l16  = lane & 15;
    const int e7   = l16 & 7;

    const u16* qbase = qk + ((size_t)(bh * 2 + 0)) * LL * HDM;
    const u16* kbase = qk + ((size_t)(bh * 2 + 1)) * LL * HDM;
    const u16* vbase = v + (size_t)bh * HDM * LL;

    const int w0 = wc * 64 + wave * 16;   // this wave's 16 queries

    // Q as B-frag: lane l16 = query col, k-slot quad*8+j = d
    short8v qfrag[2];
    qfrag[0] = *(const short8v*)(qbase + (size_t)(w0 + l16) * HDM + quad * 8);
    qfrag[1] = *(const short8v*)(qbase + (size_t)(w0 + l16) * HDM + 32 + quad * 8);

    // ones-row A-frag for col-sum MFMA: A[row=l16][k]=1 iff row==0
    short8v vones;
    {
        short o1 = (l16 == 0) ? (short)0x3F80 : (short)0;
#pragma unroll
        for (int j = 0; j < 8; ++j) vones[j] = o1;
    }

    float4v oacc[4];                  // out^T: rows d (dt*16+quad*4+r), col=query l16
#pragma unroll
    for (int dt = 0; dt < 4; ++dt) oacc[dt] = (float4v){0.f, 0.f, 0.f, 0.f};
    float4v lacc = (float4v){0.f, 0.f, 0.f, 0.f};   // row 0 = denom per query

    const int rbK   = wave * 32;
    const int lrowK = lane >> 3;          // 0..7
    const int gK    = ((lane & 7) ^ lrowK) * 8;
    const int rbV   = wave * 16;
    const int lrowV = lane >> 4;          // 0..3
    auto stage = [&](int ic, int buf) {
        const int m0 = ic * 128;
#pragma unroll
        for (int j = 0; j < 4; ++j) {
            gld_lds16(kbase + (size_t)(m0 + rbK + j * 8 + lrowK) * HDM + gK,
                      &kts[buf][rbK + j * 8][0]);
            const int vrow = j * 4 + lrowV;           // row&15 (rbV mult of 16)
            gld_lds16(vbase + (size_t)(rbV + vrow) * LL + m0 + (((lane & 15) ^ vrow) * 8),
                      &vts[buf][rbV + j * 4][0]);
        }
    };

    stage(0, 0);

    for (int ic = 0; ic < 16; ++ic) {
        const int cur = ic & 1;
        __syncthreads();   // drains vmcnt -> chunk ic staged; prev reads done

        if (ic < 15) stage(ic + 1, 1 - cur);

        // S^T = K.Q^T for all 8 key-tiles: rows = keys (quad*4+r), col = query (l16)
        float4v s[8];
#pragma unroll
        for (int mt = 0; mt < 8; ++mt) {
            s[mt] = (float4v){0.f, 0.f, 0.f, 0.f};
            short8v b0 = *(const short8v*)&kts[cur][mt * 16 + l16][((quad) ^ e7) * 8];
            s[mt] = __builtin_amdgcn_mfma_f32_16x16x32_bf16(b0, qfrag[0], s[mt], 0, 0, 0);
            short8v b1 = *(const short8v*)&kts[cur][mt * 16 + l16][((quad + 4) ^ e7) * 8];
            s[mt] = __builtin_amdgcn_mfma_f32_16x16x32_bf16(b1, qfrag[1], s[mt], 0, 0, 0);
        }

        // P^T = exp2(S^T) packed to bf16 dwords, fully in registers.
        // pk[mt][d] = keys 16*mt + 4*quad + {2d, 2d+1} for query l16.
        unsigned pk[8][2];
#pragma unroll
        for (int mt = 0; mt < 8; ++mt) {
            float p0 = __builtin_amdgcn_exp2f(s[mt][0]);
            float p1 = __builtin_amdgcn_exp2f(s[mt][1]);
            float p2 = __builtin_amdgcn_exp2f(s[mt][2]);
            float p3 = __builtin_amdgcn_exp2f(s[mt][3]);
            pk[mt][0] = (unsigned)f2u(p0) | ((unsigned)f2u(p1) << 16);
            pk[mt][1] = (unsigned)f2u(p2) | ((unsigned)f2u(p3) << 16);
        }

        // 4 PV K=32 blocks; MFMA mu covers orig tiles {2mu, 2mu+1} with
        // k-order key(8q+j) = 32mu + 16(j>>2) + 4q + (j&3) — so each lane's
        // own pk dwords ARE its B-frag, and V (pre-permuted) reads as one
        // contiguous b128 chunk c = 4mu+quad at the usual XOR position.
#pragma unroll
        for (int mu = 0; mu < 4; ++mu) {
            union { short8v v8; unsigned u[4]; } U;
            U.u[0] = pk[2 * mu][0];
            U.u[1] = pk[2 * mu][1];
            U.u[2] = pk[2 * mu + 1][0];
            U.u[3] = pk[2 * mu + 1][1];
            const short8v pb = U.v8;

            lacc = __builtin_amdgcn_mfma_f32_16x16x32_bf16(vones, pb, lacc, 0, 0, 0);

#pragma unroll
            for (int dt = 0; dt < 4; ++dt) {
                short8v va = *(const short8v*)&vts[cur][dt * 16 + l16][((4 * mu + quad) ^ l16) * 8];
                oacc[dt] = __builtin_amdgcn_mfma_f32_16x16x32_bf16(va, pb, oacc[dt], 0, 0, 0);
            }
        }
    }

    // denom for query l16 sits in lacc[0] of lane l16 (row 0 of D)
    float lsum = __shfl(lacc[0], l16);
    float inv = 1.f / lsum;
    u16* ob = newv + (size_t)b * LL * 512 + h * 64;
#pragma unroll
    for (int dt = 0; dt < 4; ++dt) {
        unsigned lo = (unsigned)f2u(oacc[dt][0] * inv) | ((unsigned)f2u(oacc[dt][1] * inv) << 16);
        unsigned hi = (unsigned)f2u(oacc[dt][2] * inv) | ((unsigned)f2u(oacc[dt][3] * inv) << 16);
        uint2 val; val.x = lo; val.y = hi;
        *(uint2*)(ob + (size_t)(w0 + l16) * 512 + dt * 16 + quad * 4) = val;
    }
}

// -------------------------------------------------------------------------
// Kernel 3: MFMA FC + swish + residual + layernorm, fused — R17-verified
// form (256 threads, full-K per wave). Output dtype per in-kernel
// detect_flag on raw x.
// -------------------------------------------------------------------------
__global__ __launch_bounds__(256) void fc_ln_mfma_kernel(
    const u16* __restrict__ newv,    // [4096][512] bf16
    const u16* __restrict__ fcw,     // [512][512] bf16
    const u16* __restrict__ fcb,     // [512]
    const u16* __restrict__ xp,      // [B][2050][512] padded bf16
    const u16* __restrict__ xraw,    // raw x input (dtype detect)
    void* __restrict__ out)          // bf16 or f32 per flag
{
    const int flag = detect_flag(xraw);
    const int l0 = blockIdx.x * 16;
    const int tid  = threadIdx.x;
    const int wave = tid >> 6;
    const int lane = tid & 63;
    const int quad = lane >> 4;
    const int l16  = lane & 15;
    const int col0 = wave * 128;

    const int bb_ = l0 >> 11;   // batch (16-row tiles never straddle)
    const size_t xbase = ((size_t)(bb_ * 2050 + (l0 & 2047) + 1)) * 512;

    __shared__ float psum[4][16], psq[4][16];

    short8v aF[16];
    const u16* arow = newv + (size_t)(l0 + l16) * 512 + quad * 8;
#pragma unroll
    for (int kc = 0; kc < 16; ++kc)
        aF[kc] = *(const short8v*)(arow + kc * 32);

    float4v acc[8];
#pragma unroll
    for (int nt = 0; nt < 8; ++nt) acc[nt] = (float4v){0.f, 0.f, 0.f, 0.f};

#pragma unroll
    for (int nt = 0; nt < 8; ++nt) {
        const u16* brow = fcw + (size_t)(col0 + nt * 16 + l16) * 512 + quad * 8;
#pragma unroll
        for (int kc = 0; kc < 16; ++kc) {
            short8v bF = *(const short8v*)(brow + kc * 32);
            acc[nt] = __builtin_amdgcn_mfma_f32_16x16x32_bf16(aF[kc], bF, acc[nt], 0, 0, 0);
        }
    }

    float z[8][4];
    float rs[4] = {0.f, 0.f, 0.f, 0.f}, rq[4] = {0.f, 0.f, 0.f, 0.f};
#pragma unroll
    for (int nt = 0; nt < 8; ++nt) {
        int col = col0 + nt * 16 + l16;
        float bb = b2f(fcb[col]);
#pragma unroll
        for (int r = 0; r < 4; ++r) {
            int row = quad * 4 + r;
            float y = acc[nt][r] + bb;
            float sw = y / (1.f + __expf(-y));    // swish
            float xv = b2f(xp[xbase + (size_t)row * 512 + col]);
            float zz = xv * 2.f + sw;
            z[nt][r] = zz;
            rs[r] += zz;
            rq[r] += zz * zz;
        }
    }
#pragma unroll
    for (int msk = 1; msk <= 8; msk <<= 1)
#pragma unroll
        for (int r = 0; r < 4; ++r) {
            rs[r] += __shfl_xor(rs[r], msk);
            rq[r] += __shfl_xor(rq[r], msk);
        }
    if (l16 == 0) {
#pragma unroll
        for (int r = 0; r < 4; ++r) {
            psum[wave][quad * 4 + r] = rs[r];
            psq[wave][quad * 4 + r]  = rq[r];
        }
    }
    __syncthreads();

    float mu[4], inv[4];
#pragma unroll
    for (int r = 0; r < 4; ++r) {
        int row = quad * 4 + r;
        float s = psum[0][row] + psum[1][row] + psum[2][row] + psum[3][row];
        float q = psq[0][row] + psq[1][row] + psq[2][row] + psq[3][row];
        float m = s * (1.f / 512.f);
        float var = q * (1.f / 512.f) - m * m;
        mu[r] = m;
        inv[r] = rsqrtf(var + 1e-5f);
    }

#pragma unroll
    for (int nt = 0; nt < 8; ++nt) {
        int col = col0 + nt * 16 + l16;
#pragma unroll
        for (int r = 0; r < 4; ++r) {
            int row = quad * 4 + r;
            float val = (z[nt][r] - mu[r]) * inv[r];
            if (flag) ((float*)out)[(size_t)(l0 + row) * 512 + col] = val;
            else      ((u16*)out)[(size_t)(l0 + row) * 512 + col] = f2u(val);
        }
    }
}

extern "C" void kernel_launch(void* const* d_in, const int* in_sizes, int n_in,
                              void* d_out, int out_size, void* d_ws, size_t ws_size,
                              hipStream_t stream) {
    (void)in_sizes; (void)n_in; (void)out_size; (void)ws_size;

    char* ws = (char*)d_ws;
    u16* xp   = (u16*)(ws + 256);        // [2][2050][512] 4,198,400 B -> ends 4,198,656
    u16* wtc  = (u16*)(ws + 4198656);    // [1536][1536] 4,718,592 B  -> ends 8,917,248
    u16* bc   = (u16*)(ws + 8917248);    // 3,072 B  -> ends 8,920,320
    u16* fwc  = (u16*)(ws + 8920320);    // 524,288 B -> ends 9,444,608
    u16* fbc  = (u16*)(ws + 9444608);    // 1,024 B  -> ends 9,445,632
    u16* qkb  = (u16*)(ws + 9445632);    // [16][2][2048][64] = 8 MB -> ends 17,834,240
    u16* vb   = (u16*)(ws + 17834240);   // [16][64][2048]    = 4 MB -> ends 22,028,544
    u16* nvc  = (u16*)(ws + 22028544);   // [2][2048][512]    = 4 MB -> ends 26,222,848

    // unified prep: 1024 (xpad) + 1152 (convw) + 129 (small) = 2305 blocks
    prep_kernel<<<dim3(2305), dim3(256), 0, stream>>>(
        d_in[0], d_in[1], d_in[2], d_in[3], d_in[4],
        xp, wtc, bc, fwc, fbc);

    conv_mfma_kernel<<<dim3(32 * 12), dim3(256), 0, stream>>>(xp, wtc, bc, qkb, vb);
    attn_mfma_kernel<<<dim3(BB * HH * (LL / 64)), dim3(256), 0, stream>>>(qkb, vb, nvc);
    fc_ln_mfma_kernel<<<dim3(256), dim3(256), 0, stream>>>(
        nvc, fwc, fbc, xp, (const u16*)d_in[0], d_out);
}

// Round 3
// 154.872 us; speedup vs baseline: 1.0873x; 1.0484x over previous
//
#include <hip/hip_runtime.h>
#include <hip/hip_bf16.h>

// Problem constants
#define BB 2
#define LL 2048
#define DD 512
#define HH 8
#define HDM 64
#define SCALE 0.022097086912079608f    // 1/sqrt(2048)
#define QSCALE 0.03187935766f          // SCALE * log2(e)  (exp2-domain softmax)

typedef __hip_bfloat16 bf16;
typedef unsigned short u16;
typedef __attribute__((ext_vector_type(8))) short short8v;   // 8 bf16 (4 VGPRs)
typedef __attribute__((ext_vector_type(4))) float float4v;   // 4 fp32 acc

// Input element counts
#define XN  2097152    // 2*2048*512
#define WN  2359296    // 1536*512*3
#define BN  1536
#define FWN 262144     // 512*512
#define FBN 512

__device__ __forceinline__ float b2f(u16 u) {
    return __uint_as_float(((unsigned int)u) << 16);
}
__device__ __forceinline__ u16 f2u(float f) {
    bf16 h = __float2bfloat16(f);
    u16 r;
    __builtin_memcpy(&r, &h, 2);
    return r;
}
__device__ __forceinline__ uint4 pack8(const float* f) {
    uint4 p;
    p.x = (unsigned)f2u(f[0]) | ((unsigned)f2u(f[1]) << 16);
    p.y = (unsigned)f2u(f[2]) | ((unsigned)f2u(f[3]) << 16);
    p.z = (unsigned)f2u(f[4]) | ((unsigned)f2u(f[5]) << 16);
    p.w = (unsigned)f2u(f[6]) | ((unsigned)f2u(f[7]) << 16);
    return p;
}

// async 16-B global -> LDS copy (lds dest = wave-uniform base + lane*16)
__device__ __forceinline__ void gld_lds16(const u16* g, u16* l) {
    __builtin_amdgcn_global_load_lds(
        (const __attribute__((address_space(1))) unsigned int*)g,
        (__attribute__((address_space(3))) unsigned int*)l, 16, 0, 0);
}

// dtype detect (f32 vs bf16 inputs), computed locally per wave — all waves
// read the same first 256 half-words of raw x, so result is uniform and
// deterministic across all blocks/kernels.
__device__ __forceinline__ int detect_flag(const u16* __restrict__ xraw) {
    int bad = 0;
    int lane = threadIdx.x & 63;
    for (int i = lane; i < 256; i += 64) {
        float v = b2f(xraw[i]);
        if (!(fabsf(v) < 100.f)) bad = 1;   // catches NaN too
    }
    return (__ballot(bad) != 0ull) ? 1 : 0;
}

__device__ __forceinline__ void conv8(const void* src, u16* dst, size_t i, int flag) {
    if (flag) {
        const float* s = (const float*)src;
        float f[8];
        float4 a = *(const float4*)(s + i);
        float4 b = *(const float4*)(s + i + 4);
        f[0] = a.x; f[1] = a.y; f[2] = a.z; f[3] = a.w;
        f[4] = b.x; f[5] = b.y; f[6] = b.z; f[7] = b.w;
        *(uint4*)(dst + i) = pack8(f);
    } else {
        *(uint4*)(dst + i) = *(const uint4*)((const u16*)src + i);
    }
}

// -------------------------------------------------------------------------
// Kernel 0: unified prep — one launch, block-range branch:
//   [0,1024)    : x -> zero-guard-padded xp[B][2050][512] (+ guard rows)
//   [1024,2176) : cnn_w canonicalize + transpose [o][i][k]->[o][k*512+i]
//   [2176,2305) : cnn_b + fc_w + fc_b converts
// -------------------------------------------------------------------------
__global__ __launch_bounds__(256) void prep_kernel(
    const void* __restrict__ xsrc, const void* __restrict__ wsrc,
    const void* __restrict__ bsrc, const void* __restrict__ fwsrc,
    const void* __restrict__ fbsrc,
    u16* __restrict__ xp, u16* __restrict__ wt,
    u16* __restrict__ bc, u16* __restrict__ fwc, u16* __restrict__ fbc)
{
    const int flag = detect_flag((const u16*)xsrc);
    const int bid = blockIdx.x;

    if (bid < 1024) {
        // ---- xpad ----
        int idx = bid * 256 + threadIdx.x;           // octet id, < 2*2048*64
        if (idx < 256) {
            int b2  = idx >> 7;
            int r2  = (idx >> 6) & 1;
            int c82 = (idx & 63) * 8;
            size_t off = ((size_t)(b2 * 2050 + (r2 ? 2049 : 0))) * 512 + c82;
            uint4 z = {0u, 0u, 0u, 0u};
            *(uint4*)(xp + off) = z;
        }
        int b   = idx / (LL * 64);
        int rem = idx - b * (LL * 64);
        int l   = rem >> 6;
        int c8  = (rem & 63) * 8;
        size_t si = ((size_t)(b * LL + l)) * 512 + c8;
        size_t di = ((size_t)(b * 2050 + l + 1)) * 512 + c8;
        if (flag) {
            const float* s = (const float*)xsrc;
            float f[8];
            float4 a = *(const float4*)(s + si);
            float4 bq = *(const float4*)(s + si + 4);
            f[0] = a.x; f[1] = a.y; f[2] = a.z; f[3] = a.w;
            f[4] = bq.x; f[5] = bq.y; f[6] = bq.z; f[7] = bq.w;
            *(uint4*)(xp + di) = pack8(f);
        } else {
            *(uint4*)(xp + di) = *(const uint4*)((const u16*)xsrc + si);
        }
    } else if (bid < 2176) {
        // ---- convw ----
        int idx = (bid - 1024) * 256 + threadIdx.x;  // < 1536*3*64
        int i8  = idx & 63;
        int rem = idx >> 6;
        int k   = rem % 3;
        int o   = rem / 3;
        float f[8];
        if (flag) {
            const float* s = (const float*)wsrc;
#pragma unroll
            for (int j = 0; j < 8; ++j) f[j] = s[(size_t)o * 1536 + (i8 * 8 + j) * 3 + k];
        } else {
            const u16* s = (const u16*)wsrc;
#pragma unroll
            for (int j = 0; j < 8; ++j) f[j] = b2f(s[(size_t)o * 1536 + (i8 * 8 + j) * 3 + k]);
        }
        *(uint4*)(wt + (size_t)o * 1536 + k * 512 + i8 * 8) = pack8(f);
    } else {
        // ---- small converts ----
        int o = (bid - 2176) * 256 + threadIdx.x;    // octet id
        if (o < BN / 8) {
            conv8(bsrc, bc, (size_t)o * 8, flag);
        } else if (o < BN / 8 + FWN / 8) {
            conv8(fwsrc, fwc, (size_t)(o - BN / 8) * 8, flag);
        } else if (o < BN / 8 + FWN / 8 + FBN / 8) {
            conv8(fbsrc, fbc, (size_t)(o - BN / 8 - FWN / 8) * 8, flag);
        }
    }
}

// -------------------------------------------------------------------------
// Kernel 1: conv GEMM — R12-verified form: 128x128 tiles, 384 blocks,
// m97-style K-loop (global_load_lds 16B, XOR bank swizzle, 1 barrier/chunk),
// LDS-transpose epilogue (coalesced qkbuf/vbuf writes), QSCALE fold into Q.
// V-columns are written in the tile-interleaved key order (verified R2) so
// the attention kernel's register-resident P^T feeds PV MFMAs directly.
// -------------------------------------------------------------------------
__global__ __launch_bounds__(256) void conv_mfma_kernel(
    const u16* __restrict__ xp,     // [B][2050][512] padded bf16
    const u16* __restrict__ wt,     // [1536][1536] = [o][k*512+i]
    const u16* __restrict__ bias,   // [1536]
    u16* __restrict__ qkbuf,        // [B*H][2][L][64]
    u16* __restrict__ vbuf)         // [B*H][64][L] (key-permuted, see above)
{
    __shared__ u16 smem[32768];     // 65536 B
    u16* Asb = smem;                // [2][128][64] unpadded, swizzled
    u16* Bsb = smem + 2 * 128 * 64; // [2][128][64] unpadded, swizzled
#define OTS 140
    u16* OT  = smem;                // [128][140] aliased after final sync

    const int blk = blockIdx.x;          // rt*12 + ct
    const int rt = blk / 12;
    const int ct = blk - rt * 12;
    const int b  = rt >> 4;
    const int l0 = (rt & 15) * 128;
    const int tid  = threadIdx.x;
    const int wave = tid >> 6;
    const int lane = tid & 63;
    const int quad = lane >> 4;
    const int l16  = lane & 15;
    const int e7   = l16 & 7;
    const int wx = wave & 1;             // n half
    const int wy = wave >> 1;            // m half

    float4v acc[4][4];
#pragma unroll
    for (int mt = 0; mt < 4; ++mt)
#pragma unroll
        for (int nt = 0; nt < 4; ++nt) acc[mt][nt] = (float4v){0.f, 0.f, 0.f, 0.f};

    const int rowW = wave * 32;
    const int lrow = lane >> 3;          // 0..7
    const int g8   = (((lane & 7) ^ lrow)) * 8;
    auto stage = [&](int kc, int buf) {
        const int slab = kc >> 3;                // conv tap k (0..2)
        const int i0   = (kc & 7) * 64;          // input-channel slice
        const u16* ga = xp + ((size_t)(b * 2050 + l0 + rowW + slab + lrow)) * 512 + i0 + g8;
        const u16* gb = wt + ((size_t)(ct * 128 + rowW + lrow)) * 1536 + kc * 64 + g8;
        u16* la = Asb + (size_t)(buf * 128 + rowW) * 64;
        u16* lb = Bsb + (size_t)(buf * 128 + rowW) * 64;
#pragma unroll
        for (int j = 0; j < 4; ++j) {
            gld_lds16(ga + (size_t)(j * 8) * 512,  la + (j * 8) * 64);
            gld_lds16(gb + (size_t)(j * 8) * 1536, lb + (j * 8) * 64);
        }
    };

    stage(0, 0);

    for (int kc = 0; kc < 24; ++kc) {
        const int cur = kc & 1;
        __syncthreads();   // drains vmcnt -> chunk kc staged; prev reads done

        if (kc < 23) stage(kc + 1, 1 - cur);

#pragma unroll
        for (int half = 0; half < 2; ++half) {
            const int p = ((half * 4 + quad) ^ e7) * 8;   // swizzled chunk
            short8v aF[4], bF[4];
#pragma unroll
            for (int mt = 0; mt < 4; ++mt)
                aF[mt] = *(const short8v*)&Asb[(size_t)(cur * 128 + wy * 64 + mt * 16 + l16) * 64 + p];
#pragma unroll
            for (int nt = 0; nt < 4; ++nt)
                bF[nt] = *(const short8v*)&Bsb[(size_t)(cur * 128 + wx * 64 + nt * 16 + l16) * 64 + p];
#pragma unroll
            for (int mt = 0; mt < 4; ++mt)
#pragma unroll
                for (int nt = 0; nt < 4; ++nt)
                    acc[mt][nt] = __builtin_amdgcn_mfma_f32_16x16x32_bf16(
                        aF[mt], bF[nt], acc[mt][nt], 0, 0, 0);
        }
    }

    // ---- epilogue stage 1: bias+swish(+QSCALE) in regs -> OT [128 l][128 o]
    __syncthreads();   // all LDS tile reads done; safe to alias as OT
    {
        const int tloc = (ct * 2 + wx) % 3;   // t for this wave's col group
#pragma unroll
        for (int nt = 0; nt < 4; ++nt) {
            int oc = wx * 64 + nt * 16 + l16;           // tile-local col
            float bb = b2f(bias[ct * 128 + oc]);
#pragma unroll
            for (int mt = 0; mt < 4; ++mt)
#pragma unroll
                for (int r = 0; r < 4; ++r) {
                    int lr = wy * 64 + mt * 16 + quad * 4 + r;   // tile-local row
                    float y = acc[mt][nt][r] + bb;
                    y = y / (1.f + __expf(-y));                  // swish
                    if (tloc == 0) y *= QSCALE;                  // fold scale*log2e into Q
                    OT[lr * OTS + oc] = f2u(y);
                }
        }
    }
    __syncthreads();

    // ---- epilogue stage 2: coalesced write-out per 64-col group
#pragma unroll
    for (int g = 0; g < 2; ++g) {
        int a  = ct * 2 + g;        // 64-col group index (0..23)
        int t  = a % 3;
        int bh = b * HH + a / 3;
        if (t != 2) {
            u16* base = qkbuf + ((size_t)((bh * 2 + t) * LL + l0)) * HDM;
#pragma unroll
            for (int it = 0; it < 4; ++it) {
                int idx = it * 256 + tid;       // 0..1023
                int l   = idx >> 3;             // 0..127
                int d8  = (idx & 7) * 8;        // 0..56
                uint4 val = *(const uint4*)&OT[l * OTS + g * 64 + d8];
                *(uint4*)(base + (size_t)l * HDM + d8) = val;
            }
        } else {
            u16* base = vbuf + ((size_t)(bh * HDM)) * LL + l0;
#pragma unroll
            for (int it = 0; it < 4; ++it) {
                int idx = it * 256 + tid;       // 0..1023
                int dd  = idx >> 4;             // 0..63
                int p   = idx & 15;             // 8-col group within 128 tile
                int l8  = p * 8;
                u16 tmp[8];
#pragma unroll
                for (int j = 0; j < 8; ++j) tmp[j] = OT[(l8 + j) * OTS + g * 64 + dd];
                // tile-interleaved key permute within each 32-key group:
                // orig w -> n = 8*((w>>2)&3) + 4*(w>>4) + (w&3)
                int a32 = p >> 2;                // 32-key group
                int pb_ = p & 3;
                int q2  = (2 * pb_) & 3;
                int h2  = pb_ >> 1;
                int n0  = 32 * a32 + 8 * q2 + 4 * h2;   // j=0..3 run
                uint2 v0, v1;
                v0.x = (unsigned)tmp[0] | ((unsigned)tmp[1] << 16);
                v0.y = (unsigned)tmp[2] | ((unsigned)tmp[3] << 16);
                v1.x = (unsigned)tmp[4] | ((unsigned)tmp[5] << 16);
                v1.y = (unsigned)tmp[6] | ((unsigned)tmp[7] << 16);
                *(uint2*)(base + (size_t)dd * LL + n0)     = v0;   // j=0..3
                *(uint2*)(base + (size_t)dd * LL + n0 + 8) = v1;   // j=4..7
            }
        }
    }
#undef OTS
}

// -------------------------------------------------------------------------
// Kernel 2: MFMA flash attention — dual-Q (32 queries/wave, every K/V LDS
// fragment read feeds 2 MFMAs) + 2-way split-K (static softmax => partials
// are purely additive; combine = one LDS exchange + add). 256 blocks x 512
// threads: wave = (kgroup = w>>2, qgroup = w&3); each kgroup double-buffers
// its own 64-key K[64][64]/V[64][64] tiles (64 KB LDS, 1 block/CU,
// 2 waves/SIMD — one per kgroup so phases interleave). Register-resident
// P^T (R2-verified layout) and key-permuted V unchanged.
// -------------------------------------------------------------------------
__global__ __launch_bounds__(512) void attn_mfma_kernel(
    const u16* __restrict__ qk,    // [B*H][2][L][64]
    const u16* __restrict__ v,     // [B*H][64][L] key-permuted
    u16* __restrict__ newv)        // [B][L][512]
{
    __shared__ u16 smem[32768];                                   // 64 KB pool
    u16 (*kts)[2][64][64] = (u16 (*)[2][64][64])smem;             // [kg][buf][key][d]
    u16 (*vts)[2][64][64] = (u16 (*)[2][64][64])(smem + 16384);   // [kg][buf][d][key]

    // bijective XCD swizzle (256 % 8 == 0): 16 blocks of one bh -> 2 bh/XCD
    const int lb = ((blockIdx.x & 7) << 5) + (blockIdx.x >> 3);
    const int bh = lb >> 4;              // b*8 + h
    const int qc = lb & 15;              // 128-query chunk
    const int b  = bh >> 3;
    const int h  = bh & 7;
    const int tid  = threadIdx.x;
    const int wave = tid >> 6;           // 0..7
    const int kg   = wave >> 2;          // split-K group
    const int qg   = wave & 3;           // query group
    const int lane = tid & 63;
    const int quad = lane >> 4;
    const int l16  = lane & 15;
    const int e7   = l16 & 7;

    const u16* qbase = qk + ((size_t)(bh * 2 + 0)) * LL * HDM;
    const u16* kbase = qk + ((size_t)(bh * 2 + 1)) * LL * HDM;
    const u16* vbase = v + (size_t)bh * HDM * LL;

    const int q0 = qc * 128 + qg * 32;   // wave's 32 queries (2 subgroups of 16)

    // Q as B-frag per subgroup: lane l16 = query col, k-slot quad*8+j = d
    short8v qfrag[2][2];
#pragma unroll
    for (int sg = 0; sg < 2; ++sg) {
        const u16* qr = qbase + (size_t)(q0 + sg * 16 + l16) * HDM + quad * 8;
        qfrag[sg][0] = *(const short8v*)(qr);
        qfrag[sg][1] = *(const short8v*)(qr + 32);
    }

    // ones-row A-frag for col-sum MFMA: A[row=l16][k]=1 iff row==0
    short8v vones;
    {
        short o1 = (l16 == 0) ? (short)0x3F80 : (short)0;
#pragma unroll
        for (int j = 0; j < 8; ++j) vones[j] = o1;
    }

    float4v oacc[2][4];                  // [sg][dt] out^T rows d, col=query l16
    float4v lacc[2];
#pragma unroll
    for (int sg = 0; sg < 2; ++sg) {
        lacc[sg] = (float4v){0.f, 0.f, 0.f, 0.f};
#pragma unroll
        for (int dt = 0; dt < 4; ++dt) oacc[sg][dt] = (float4v){0.f, 0.f, 0.f, 0.f};
    }

    // staging: 4 waves of a kgroup cooperate on K 64x64 and V 64x64.
    // LDS[row][chunk c] holds global chunk c ^ (row&7)  (row&7 == lane>>3).
    const int rr  = qg * 8 + (lane >> 3);
    const int sw8 = ((lane & 7) ^ (lane >> 3)) * 8;
    auto stage = [&](int ic, int buf) {
        const int m0 = ic * 64;
#pragma unroll
        for (int r = 0; r < 2; ++r) {
            gld_lds16(kbase + (size_t)(m0 + r * 32 + rr) * HDM + sw8,
                      &kts[kg][buf][r * 32 + qg * 8][0]);
            gld_lds16(vbase + (size_t)(r * 32 + rr) * LL + m0 + sw8,
                      &vts[kg][buf][r * 32 + qg * 8][0]);
        }
    };

    stage(kg, 0);   // kgroup kg handles chunks 2*i + kg, i = 0..15

    for (int i = 0; i < 16; ++i) {
        const int cur = i & 1;
        __syncthreads();   // drains vmcnt -> chunk staged; prev reads done

        if (i < 15) stage(2 * (i + 1) + kg, 1 - cur);

        // S^T = K.Q^T: rows = keys (quad*4+r), col = query (l16), per sg
        float4v s[2][4];
#pragma unroll
        for (int mt = 0; mt < 4; ++mt) {
            short8v b0 = *(const short8v*)&kts[kg][cur][mt * 16 + l16][((quad) ^ e7) * 8];
            short8v b1 = *(const short8v*)&kts[kg][cur][mt * 16 + l16][((quad + 4) ^ e7) * 8];
#pragma unroll
            for (int sg = 0; sg < 2; ++sg) {
                float4v t = (float4v){0.f, 0.f, 0.f, 0.f};
                t = __builtin_amdgcn_mfma_f32_16x16x32_bf16(b0, qfrag[sg][0], t, 0, 0, 0);
                t = __builtin_amdgcn_mfma_f32_16x16x32_bf16(b1, qfrag[sg][1], t, 0, 0, 0);
                s[sg][mt] = t;
            }
        }

        // P^T = exp2(S^T) packed to bf16 dwords, fully in registers
        unsigned pk[2][4][2];
#pragma unroll
        for (int sg = 0; sg < 2; ++sg)
#pragma unroll
            for (int mt = 0; mt < 4; ++mt) {
                float p0 = __builtin_amdgcn_exp2f(s[sg][mt][0]);
                float p1 = __builtin_amdgcn_exp2f(s[sg][mt][1]);
                float p2 = __builtin_amdgcn_exp2f(s[sg][mt][2]);
                float p3 = __builtin_amdgcn_exp2f(s[sg][mt][3]);
                pk[sg][mt][0] = (unsigned)f2u(p0) | ((unsigned)f2u(p1) << 16);
                pk[sg][mt][1] = (unsigned)f2u(p2) | ((unsigned)f2u(p3) << 16);
            }

        // 2 PV K=32 blocks per 64-key chunk; each V A-frag read feeds 2 sg
#pragma unroll
        for (int mu = 0; mu < 2; ++mu) {
            short8v pb[2];
#pragma unroll
            for (int sg = 0; sg < 2; ++sg) {
                union { short8v v8; unsigned u[4]; } U;
                U.u[0] = pk[sg][2 * mu][0];
                U.u[1] = pk[sg][2 * mu][1];
                U.u[2] = pk[sg][2 * mu + 1][0];
                U.u[3] = pk[sg][2 * mu + 1][1];
                pb[sg] = U.v8;
                lacc[sg] = __builtin_amdgcn_mfma_f32_16x16x32_bf16(vones, pb[sg], lacc[sg], 0, 0, 0);
            }
#pragma unroll
            for (int dt = 0; dt < 4; ++dt) {
                short8v va = *(const short8v*)&vts[kg][cur][dt * 16 + l16][((mu * 4 + quad) ^ e7) * 8];
#pragma unroll
                for (int sg = 0; sg < 2; ++sg)
                    oacc[sg][dt] = __builtin_amdgcn_mfma_f32_16x16x32_bf16(va, pb[sg], oacc[sg][dt], 0, 0, 0);
            }
        }
    }

    // split-K combine: static softmax => oacc/denoms add directly
    float dnm[2];
#pragma unroll
    for (int sg = 0; sg < 2; ++sg) dnm[sg] = __shfl(lacc[sg][0], l16);

    __syncthreads();   // all tile reads done; alias pool as exchange
    float* xch = (float*)smem;           // [uw 4][34][64] f32 = 34,816 B
    if (kg == 1) {
#pragma unroll
        for (int sg = 0; sg < 2; ++sg) {
#pragma unroll
            for (int dt = 0; dt < 4; ++dt)
#pragma unroll
                for (int r = 0; r < 4; ++r)
                    xch[((qg * 34 + (sg * 16 + dt * 4 + r)) << 6) + lane] = oacc[sg][dt][r];
            xch[((qg * 34 + 32 + sg) << 6) + lane] = dnm[sg];
        }
    }
    __syncthreads();
    if (kg == 0) {
        u16* ob = newv + (size_t)b * LL * 512 + h * 64;
#pragma unroll
        for (int sg = 0; sg < 2; ++sg) {
            float dt2 = dnm[sg] + xch[((qg * 34 + 32 + sg) << 6) + lane];
            float inv = 1.f / dt2;
            const size_t orow = (size_t)(q0 + sg * 16 + l16) * 512 + quad * 4;
#pragma unroll
            for (int dt = 0; dt < 4; ++dt) {
                float o0 = oacc[sg][dt][0] + xch[((qg * 34 + (sg * 16 + dt * 4 + 0)) << 6) + lane];
                float o1 = oacc[sg][dt][1] + xch[((qg * 34 + (sg * 16 + dt * 4 + 1)) << 6) + lane];
                float o2 = oacc[sg][dt][2] + xch[((qg * 34 + (sg * 16 + dt * 4 + 2)) << 6) + lane];
                float o3 = oacc[sg][dt][3] + xch[((qg * 34 + (sg * 16 + dt * 4 + 3)) << 6) + lane];
                unsigned lo = (unsigned)f2u(o0 * inv) | ((unsigned)f2u(o1 * inv) << 16);
                unsigned hi = (unsigned)f2u(o2 * inv) | ((unsigned)f2u(o3 * inv) << 16);
                uint2 val; val.x = lo; val.y = hi;
                *(uint2*)(ob + orow + dt * 16) = val;
            }
        }
    }
}

// -------------------------------------------------------------------------
// Kernel 3: MFMA FC + swish + residual + layernorm, fused — R17-verified
// form (256 threads, full-K per wave). Output dtype per in-kernel
// detect_flag on raw x.
// -------------------------------------------------------------------------
__global__ __launch_bounds__(256) void fc_ln_mfma_kernel(
    const u16* __restrict__ newv,    // [4096][512] bf16
    const u16* __restrict__ fcw,     // [512][512] bf16
    const u16* __restrict__ fcb,     // [512]
    const u16* __restrict__ xp,      // [B][2050][512] padded bf16
    const u16* __restrict__ xraw,    // raw x input (dtype detect)
    void* __restrict__ out)          // bf16 or f32 per flag
{
    const int flag = detect_flag(xraw);
    const int l0 = blockIdx.x * 16;
    const int tid  = threadIdx.x;
    const int wave = tid >> 6;
    const int lane = tid & 63;
    const int quad = lane >> 4;
    const int l16  = lane & 15;
    const int col0 = wave * 128;

    const int bb_ = l0 >> 11;   // batch (16-row tiles never straddle)
    const size_t xbase = ((size_t)(bb_ * 2050 + (l0 & 2047) + 1)) * 512;

    __shared__ float psum[4][16], psq[4][16];

    short8v aF[16];
    const u16* arow = newv + (size_t)(l0 + l16) * 512 + quad * 8;
#pragma unroll
    for (int kc = 0; kc < 16; ++kc)
        aF[kc] = *(const short8v*)(arow + kc * 32);

    float4v acc[8];
#pragma unroll
    for (int nt = 0; nt < 8; ++nt) acc[nt] = (float4v){0.f, 0.f, 0.f, 0.f};

#pragma unroll
    for (int nt = 0; nt < 8; ++nt) {
        const u16* brow = fcw + (size_t)(col0 + nt * 16 + l16) * 512 + quad * 8;
#pragma unroll
        for (int kc = 0; kc < 16; ++kc) {
            short8v bF = *(const short8v*)(brow + kc * 32);
            acc[nt] = __builtin_amdgcn_mfma_f32_16x16x32_bf16(aF[kc], bF, acc[nt], 0, 0, 0);
        }
    }

    float z[8][4];
    float rs[4] = {0.f, 0.f, 0.f, 0.f}, rq[4] = {0.f, 0.f, 0.f, 0.f};
#pragma unroll
    for (int nt = 0; nt < 8; ++nt) {
        int col = col0 + nt * 16 + l16;
        float bb = b2f(fcb[col]);
#pragma unroll
        for (int r = 0; r < 4; ++r) {
            int row = quad * 4 + r;
            float y = acc[nt][r] + bb;
            float sw = y / (1.f + __expf(-y));    // swish
            float xv = b2f(xp[xbase + (size_t)row * 512 + col]);
            float zz = xv * 2.f + sw;
            z[nt][r] = zz;
            rs[r] += zz;
            rq[r] += zz * zz;
        }
    }
#pragma unroll
    for (int msk = 1; msk <= 8; msk <<= 1)
#pragma unroll
        for (int r = 0; r < 4; ++r) {
            rs[r] += __shfl_xor(rs[r], msk);
            rq[r] += __shfl_xor(rq[r], msk);
        }
    if (l16 == 0) {
#pragma unroll
        for (int r = 0; r < 4; ++r) {
            psum[wave][quad * 4 + r] = rs[r];
            psq[wave][quad * 4 + r]  = rq[r];
        }
    }
    __syncthreads();

    float mu[4], inv[4];
#pragma unroll
    for (int r = 0; r < 4; ++r) {
        int row = quad * 4 + r;
        float s = psum[0][row] + psum[1][row] + psum[2][row] + psum[3][row];
        float q = psq[0][row] + psq[1][row] + psq[2][row] + psq[3][row];
        float m = s * (1.f / 512.f);
        float var = q * (1.f / 512.f) - m * m;
        mu[r] = m;
        inv[r] = rsqrtf(var + 1e-5f);
    }

#pragma unroll
    for (int nt = 0; nt < 8; ++nt) {
        int col = col0 + nt * 16 + l16;
#pragma unroll
        for (int r = 0; r < 4; ++r) {
            int row = quad * 4 + r;
            float val = (z[nt][r] - mu[r]) * inv[r];
            if (flag) ((float*)out)[(size_t)(l0 + row) * 512 + col] = val;
            else      ((u16*)out)[(size_t)(l0 + row) * 512 + col] = f2u(val);
        }
    }
}

extern "C" void kernel_launch(void* const* d_in, const int* in_sizes, int n_in,
                              void* d_out, int out_size, void* d_ws, size_t ws_size,
                              hipStream_t stream) {
    (void)in_sizes; (void)n_in; (void)out_size; (void)ws_size;

    char* ws = (char*)d_ws;
    u16* xp   = (u16*)(ws + 256);        // [2][2050][512] 4,198,400 B -> ends 4,198,656
    u16* wtc  = (u16*)(ws + 4198656);    // [1536][1536] 4,718,592 B  -> ends 8,917,248
    u16* bc   = (u16*)(ws + 8917248);    // 3,072 B  -> ends 8,920,320
    u16* fwc  = (u16*)(ws + 8920320);    // 524,288 B -> ends 9,444,608
    u16* fbc  = (u16*)(ws + 9444608);    // 1,024 B  -> ends 9,445,632
    u16* qkb  = (u16*)(ws + 9445632);    // [16][2][2048][64] = 8 MB -> ends 17,834,240
    u16* vb   = (u16*)(ws + 17834240);   // [16][64][2048]    = 4 MB -> ends 22,028,544
    u16* nvc  = (u16*)(ws + 22028544);   // [2][2048][512]    = 4 MB -> ends 26,222,848

    // unified prep: 1024 (xpad) + 1152 (convw) + 129 (small) = 2305 blocks
    prep_kernel<<<dim3(2305), dim3(256), 0, stream>>>(
        d_in[0], d_in[1], d_in[2], d_in[3], d_in[4],
        xp, wtc, bc, fwc, fbc);

    conv_mfma_kernel<<<dim3(32 * 12), dim3(256), 0, stream>>>(xp, wtc, bc, qkb, vb);
    attn_mfma_kernel<<<dim3(256), dim3(512), 0, stream>>>(qkb, vb, nvc);
    fc_ln_mfma_kernel<<<dim3(256), dim3(256), 0, stream>>>(
        nvc, fwc, fbc, xp, (const u16*)d_in[0], d_out);
}

// Round 5
// 149.108 us; speedup vs baseline: 1.1294x; 1.0387x over previous
//
#include <hip/hip_runtime.h>
#include <hip/hip_bf16.h>

// Problem constants
#define BB 2
#define LL 2048
#define DD 512
#define HH 8
#define HDM 64
#define SCALE 0.022097086912079608f    // 1/sqrt(2048)
#define QSCALE 0.03187935766f          // SCALE * log2(e)  (exp2-domain softmax)

typedef __hip_bfloat16 bf16;
typedef unsigned short u16;
typedef __attribute__((ext_vector_type(8))) short short8v;   // 8 bf16 (4 VGPRs)
typedef __attribute__((ext_vector_type(4))) float float4v;   // 4 fp32 acc

// Input element counts
#define XN  2097152    // 2*2048*512
#define WN  2359296    // 1536*512*3
#define BN  1536
#define FWN 262144     // 512*512
#define FBN 512

__device__ __forceinline__ float b2f(u16 u) {
    return __uint_as_float(((unsigned int)u) << 16);
}
__device__ __forceinline__ u16 f2u(float f) {
    bf16 h = __float2bfloat16(f);
    u16 r;
    __builtin_memcpy(&r, &h, 2);
    return r;
}
__device__ __forceinline__ uint4 pack8(const float* f) {
    uint4 p;
    p.x = (unsigned)f2u(f[0]) | ((unsigned)f2u(f[1]) << 16);
    p.y = (unsigned)f2u(f[2]) | ((unsigned)f2u(f[3]) << 16);
    p.z = (unsigned)f2u(f[4]) | ((unsigned)f2u(f[5]) << 16);
    p.w = (unsigned)f2u(f[6]) | ((unsigned)f2u(f[7]) << 16);
    return p;
}

// async 16-B global -> LDS copy (lds dest = wave-uniform base + lane*16)
__device__ __forceinline__ void gld_lds16(const u16* g, u16* l) {
    __builtin_amdgcn_global_load_lds(
        (const __attribute__((address_space(1))) unsigned int*)g,
        (__attribute__((address_space(3))) unsigned int*)l, 16, 0, 0);
}

// dtype detect (f32 vs bf16 inputs), computed locally per wave — all waves
// read the same first 256 half-words of raw x, so result is uniform and
// deterministic across all blocks/kernels.
__device__ __forceinline__ int detect_flag(const u16* __restrict__ xraw) {
    int bad = 0;
    int lane = threadIdx.x & 63;
    for (int i = lane; i < 256; i += 64) {
        float v = b2f(xraw[i]);
        if (!(fabsf(v) < 100.f)) bad = 1;   // catches NaN too
    }
    return (__ballot(bad) != 0ull) ? 1 : 0;
}

__device__ __forceinline__ void conv8(const void* src, u16* dst, size_t i, int flag) {
    if (flag) {
        const float* s = (const float*)src;
        float f[8];
        float4 a = *(const float4*)(s + i);
        float4 b = *(const float4*)(s + i + 4);
        f[0] = a.x; f[1] = a.y; f[2] = a.z; f[3] = a.w;
        f[4] = b.x; f[5] = b.y; f[6] = b.z; f[7] = b.w;
        *(uint4*)(dst + i) = pack8(f);
    } else {
        *(uint4*)(dst + i) = *(const uint4*)((const u16*)src + i);
    }
}

// -------------------------------------------------------------------------
// Kernel 0: unified prep — one launch, block-range branch:
//   [0,1024)    : x -> zero-guard-padded xp[B][2050][512] (+ guard rows)
//   [1024,1216) : cnn_w canonicalize + transpose via LDS (coalesced loads)
//   [1216,1345) : cnn_b + fc_w + fc_b converts
// -------------------------------------------------------------------------
__global__ __launch_bounds__(256) void prep_kernel(
    const void* __restrict__ xsrc, const void* __restrict__ wsrc,
    const void* __restrict__ bsrc, const void* __restrict__ fwsrc,
    const void* __restrict__ fbsrc,
    u16* __restrict__ xp, u16* __restrict__ wt,
    u16* __restrict__ bc, u16* __restrict__ fwc, u16* __restrict__ fbc)
{
    const int flag = detect_flag((const u16*)xsrc);
    const int bid = blockIdx.x;

    if (bid < 1024) {
        // ---- xpad ----
        int idx = bid * 256 + threadIdx.x;           // octet id, < 2*2048*64
        if (idx < 256) {
            int b2  = idx >> 7;
            int r2  = (idx >> 6) & 1;
            int c82 = (idx & 63) * 8;
            size_t off = ((size_t)(b2 * 2050 + (r2 ? 2049 : 0))) * 512 + c82;
            uint4 z = {0u, 0u, 0u, 0u};
            *(uint4*)(xp + off) = z;
        }
        int b   = idx / (LL * 64);
        int rem = idx - b * (LL * 64);
        int l   = rem >> 6;
        int c8  = (rem & 63) * 8;
        size_t si = ((size_t)(b * LL + l)) * 512 + c8;
        size_t di = ((size_t)(b * 2050 + l + 1)) * 512 + c8;
        if (flag) {
            const float* s = (const float*)xsrc;
            float f[8];
            float4 a = *(const float4*)(s + si);
            float4 bq = *(const float4*)(s + si + 4);
            f[0] = a.x; f[1] = a.y; f[2] = a.z; f[3] = a.w;
            f[4] = bq.x; f[5] = bq.y; f[6] = bq.z; f[7] = bq.w;
            *(uint4*)(xp + di) = pack8(f);
        } else {
            *(uint4*)(xp + di) = *(const uint4*)((const u16*)xsrc + si);
        }
    } else if (bid < 1216) {
        // ---- convw via LDS transpose: 8 o-rows per block, coalesced ----
        __shared__ u16 wl[8 * 1536];                 // 24 KB, [row][i*3+k]
        const int t  = threadIdx.x;
        const int o0 = (bid - 1024) * 8;
        if (flag) {
            const float4* s4 = (const float4*)((const float*)wsrc + (size_t)o0 * 1536);
#pragma unroll
            for (int v = 0; v < 12; ++v) {           // 3072 float4 total
                int i4 = v * 256 + t;
                float4 q = s4[i4];
                uint2 p;
                p.x = (unsigned)f2u(q.x) | ((unsigned)f2u(q.y) << 16);
                p.y = (unsigned)f2u(q.z) | ((unsigned)f2u(q.w) << 16);
                *(uint2*)&wl[i4 * 4] = p;
            }
        } else {
            const uint4* s8 = (const uint4*)((const u16*)wsrc + (size_t)o0 * 1536);
#pragma unroll
            for (int v = 0; v < 6; ++v) {            // 1536 uint4 total
                int i8 = v * 256 + t;
                *(uint4*)&wl[i8 * 8] = s8[i8];
            }
        }
        __syncthreads();
#pragma unroll
        for (int v = 0; v < 6; ++v) {                // 1536 output octets
            int oct = v * 256 + t;
            int row = oct / 192;
            int rem = oct - row * 192;
            int k   = rem >> 6;
            int i8  = rem & 63;
            u16 tmp[8];
#pragma unroll
            for (int j = 0; j < 8; ++j) tmp[j] = wl[row * 1536 + (i8 * 8 + j) * 3 + k];
            uint4 val;
            val.x = (unsigned)tmp[0] | ((unsigned)tmp[1] << 16);
            val.y = (unsigned)tmp[2] | ((unsigned)tmp[3] << 16);
            val.z = (unsigned)tmp[4] | ((unsigned)tmp[5] << 16);
            val.w = (unsigned)tmp[6] | ((unsigned)tmp[7] << 16);
            *(uint4*)(wt + (size_t)(o0 + row) * 1536 + k * 512 + i8 * 8) = val;
        }
    } else {
        // ---- small converts ----
        int o = (bid - 1216) * 256 + threadIdx.x;    // octet id
        if (o < BN / 8) {
            conv8(bsrc, bc, (size_t)o * 8, flag);
        } else if (o < BN / 8 + FWN / 8) {
            conv8(fwsrc, fwc, (size_t)(o - BN / 8) * 8, flag);
        } else if (o < BN / 8 + FWN / 8 + FBN / 8) {
            conv8(fbsrc, fbc, (size_t)(o - BN / 8 - FWN / 8) * 8, flag);
        }
    }
}

// -------------------------------------------------------------------------
// Kernel 1: conv GEMM — R12-verified form: 128x128 tiles, 384 blocks,
// m97-style K-loop (global_load_lds 16B, XOR bank swizzle, 1 barrier/chunk),
// LDS-transpose epilogue (coalesced qkbuf/vbuf writes), QSCALE fold into Q.
// V-columns are written in the tile-interleaved key order (verified R2) so
// the attention kernel's register-resident P^T feeds PV MFMAs directly.
// -------------------------------------------------------------------------
__global__ __launch_bounds__(256) void conv_mfma_kernel(
    const u16* __restrict__ xp,     // [B][2050][512] padded bf16
    const u16* __restrict__ wt,     // [1536][1536] = [o][k*512+i]
    const u16* __restrict__ bias,   // [1536]
    u16* __restrict__ qkbuf,        // [B*H][2][L][64]
    u16* __restrict__ vbuf)         // [B*H][64][L] (key-permuted, see above)
{
    __shared__ u16 smem[32768];     // 65536 B
    u16* Asb = smem;                // [2][128][64] unpadded, swizzled
    u16* Bsb = smem + 2 * 128 * 64; // [2][128][64] unpadded, swizzled
#define OTS 140
    u16* OT  = smem;                // [128][140] aliased after final sync

    const int blk = blockIdx.x;          // rt*12 + ct
    const int rt = blk / 12;
    const int ct = blk - rt * 12;
    const int b  = rt >> 4;
    const int l0 = (rt & 15) * 128;
    const int tid  = threadIdx.x;
    const int wave = tid >> 6;
    const int lane = tid & 63;
    const int quad = lane >> 4;
    const int l16  = lane & 15;
    const int e7   = l16 & 7;
    const int wx = wave & 1;             // n half
    const int wy = wave >> 1;            // m half

    float4v acc[4][4];
#pragma unroll
    for (int mt = 0; mt < 4; ++mt)
#pragma unroll
        for (int nt = 0; nt < 4; ++nt) acc[mt][nt] = (float4v){0.f, 0.f, 0.f, 0.f};

    const int rowW = wave * 32;
    const int lrow = lane >> 3;          // 0..7
    const int g8   = (((lane & 7) ^ lrow)) * 8;
    auto stage = [&](int kc, int buf) {
        const int slab = kc >> 3;                // conv tap k (0..2)
        const int i0   = (kc & 7) * 64;          // input-channel slice
        const u16* ga = xp + ((size_t)(b * 2050 + l0 + rowW + slab + lrow)) * 512 + i0 + g8;
        const u16* gb = wt + ((size_t)(ct * 128 + rowW + lrow)) * 1536 + kc * 64 + g8;
        u16* la = Asb + (size_t)(buf * 128 + rowW) * 64;
        u16* lb = Bsb + (size_t)(buf * 128 + rowW) * 64;
#pragma unroll
        for (int j = 0; j < 4; ++j) {
            gld_lds16(ga + (size_t)(j * 8) * 512,  la + (j * 8) * 64);
            gld_lds16(gb + (size_t)(j * 8) * 1536, lb + (j * 8) * 64);
        }
    };

    stage(0, 0);

    for (int kc = 0; kc < 24; ++kc) {
        const int cur = kc & 1;
        __syncthreads();   // drains vmcnt -> chunk kc staged; prev reads done

        if (kc < 23) stage(kc + 1, 1 - cur);

#pragma unroll
        for (int half = 0; half < 2; ++half) {
            const int p = ((half * 4 + quad) ^ e7) * 8;   // swizzled chunk
            short8v aF[4], bF[4];
#pragma unroll
            for (int mt = 0; mt < 4; ++mt)
                aF[mt] = *(const short8v*)&Asb[(size_t)(cur * 128 + wy * 64 + mt * 16 + l16) * 64 + p];
#pragma unroll
            for (int nt = 0; nt < 4; ++nt)
                bF[nt] = *(const short8v*)&Bsb[(size_t)(cur * 128 + wx * 64 + nt * 16 + l16) * 64 + p];
#pragma unroll
            for (int mt = 0; mt < 4; ++mt)
#pragma unroll
                for (int nt = 0; nt < 4; ++nt)
                    acc[mt][nt] = __builtin_amdgcn_mfma_f32_16x16x32_bf16(
                        aF[mt], bF[nt], acc[mt][nt], 0, 0, 0);
        }
    }

    // ---- epilogue stage 1: bias+swish(+QSCALE) in regs -> OT [128 l][128 o]
    __syncthreads();   // all LDS tile reads done; safe to alias as OT
    {
        const int tloc = (ct * 2 + wx) % 3;   // t for this wave's col group
#pragma unroll
        for (int nt = 0; nt < 4; ++nt) {
            int oc = wx * 64 + nt * 16 + l16;           // tile-local col
            float bb = b2f(bias[ct * 128 + oc]);
#pragma unroll
            for (int mt = 0; mt < 4; ++mt)
#pragma unroll
                for (int r = 0; r < 4; ++r) {
                    int lr = wy * 64 + mt * 16 + quad * 4 + r;   // tile-local row
                    float y = acc[mt][nt][r] + bb;
                    y = y / (1.f + __expf(-y));                  // swish
                    if (tloc == 0) y *= QSCALE;                  // fold scale*log2e into Q
                    OT[lr * OTS + oc] = f2u(y);
                }
        }
    }
    __syncthreads();

    // ---- epilogue stage 2: coalesced write-out per 64-col group
#pragma unroll
    for (int g = 0; g < 2; ++g) {
        int a  = ct * 2 + g;        // 64-col group index (0..23)
        int t  = a % 3;
        int bh = b * HH + a / 3;
        if (t != 2) {
            u16* base = qkbuf + ((size_t)((bh * 2 + t) * LL + l0)) * HDM;
#pragma unroll
            for (int it = 0; it < 4; ++it) {
                int idx = it * 256 + tid;       // 0..1023
                int l   = idx >> 3;             // 0..127
                int d8  = (idx & 7) * 8;        // 0..56
                uint4 val = *(const uint4*)&OT[l * OTS + g * 64 + d8];
                *(uint4*)(base + (size_t)l * HDM + d8) = val;
            }
        } else {
            u16* base = vbuf + ((size_t)(bh * HDM)) * LL + l0;
#pragma unroll
            for (int it = 0; it < 4; ++it) {
                int idx = it * 256 + tid;       // 0..1023
                int dd  = idx >> 4;             // 0..63
                int p   = idx & 15;             // 8-col group within 128 tile
                int l8  = p * 8;
                u16 tmp[8];
#pragma unroll
                for (int j = 0; j < 8; ++j) tmp[j] = OT[(l8 + j) * OTS + g * 64 + dd];
                // tile-interleaved key permute within each 32-key group:
                // orig w -> n = 8*((w>>2)&3) + 4*(w>>4) + (w&3)
                int a32 = p >> 2;                // 32-key group
                int pb_ = p & 3;
                int q2  = (2 * pb_) & 3;
                int h2  = pb_ >> 1;
                int n0  = 32 * a32 + 8 * q2 + 4 * h2;   // j=0..3 run
                uint2 v0, v1;
                v0.x = (unsigned)tmp[0] | ((unsigned)tmp[1] << 16);
                v0.y = (unsigned)tmp[2] | ((unsigned)tmp[3] << 16);
                v1.x = (unsigned)tmp[4] | ((unsigned)tmp[5] << 16);
                v1.y = (unsigned)tmp[6] | ((unsigned)tmp[7] << 16);
                *(uint2*)(base + (size_t)dd * LL + n0)     = v0;   // j=0..3
                *(uint2*)(base + (size_t)dd * LL + n0 + 8) = v1;   // j=4..7
            }
        }
    }
#undef OTS
}

// -------------------------------------------------------------------------
// Kernel 2: MFMA flash attention — dual-Q (32 queries/wave, every K/V LDS
// fragment read feeds 2 MFMAs) + 2-way split-K (static softmax => partials
// are purely additive; combine = one LDS exchange + add). 256 blocks x 512
// threads: wave = (kgroup = w>>2, qgroup = w&3); each kgroup double-buffers
// its own 64-key K[64][64]/V[64][64] tiles (64 KB LDS, 1 block/CU,
// 2 waves/SIMD — one per kgroup so phases interleave). Register-resident
// P^T (R2-verified layout) and key-permuted V unchanged. R3-verified.
// -------------------------------------------------------------------------
__global__ __launch_bounds__(512) void attn_mfma_kernel(
    const u16* __restrict__ qk,    // [B*H][2][L][64]
    const u16* __restrict__ v,     // [B*H][64][L] key-permuted
    u16* __restrict__ newv)        // [B][L][512]
{
    __shared__ u16 smem[32768];                                   // 64 KB pool
    u16 (*kts)[2][64][64] = (u16 (*)[2][64][64])smem;             // [kg][buf][key][d]
    u16 (*vts)[2][64][64] = (u16 (*)[2][64][64])(smem + 16384);   // [kg][buf][d][key]

    // bijective XCD swizzle (256 % 8 == 0): 16 blocks of one bh -> 2 bh/XCD
    const int lb = ((blockIdx.x & 7) << 5) + (blockIdx.x >> 3);
    const int bh = lb >> 4;              // b*8 + h
    const int qc = lb & 15;              // 128-query chunk
    const int b  = bh >> 3;
    const int h  = bh & 7;
    const int tid  = threadIdx.x;
    const int wave = tid >> 6;           // 0..7
    const int kg   = wave >> 2;          // split-K group
    const int qg   = wave & 3;           // query group
    const int lane = tid & 63;
    const int quad = lane >> 4;
    const int l16  = lane & 15;
    const int e7   = l16 & 7;

    const u16* qbase = qk + ((size_t)(bh * 2 + 0)) * LL * HDM;
    const u16* kbase = qk + ((size_t)(bh * 2 + 1)) * LL * HDM;
    const u16* vbase = v + (size_t)bh * HDM * LL;

    const int q0 = qc * 128 + qg * 32;   // wave's 32 queries (2 subgroups of 16)

    // Q as B-frag per subgroup: lane l16 = query col, k-slot quad*8+j = d
    short8v qfrag[2][2];
#pragma unroll
    for (int sg = 0; sg < 2; ++sg) {
        const u16* qr = qbase + (size_t)(q0 + sg * 16 + l16) * HDM + quad * 8;
        qfrag[sg][0] = *(const short8v*)(qr);
        qfrag[sg][1] = *(const short8v*)(qr + 32);
    }

    // ones-row A-frag for col-sum MFMA: A[row=l16][k]=1 iff row==0
    short8v vones;
    {
        short o1 = (l16 == 0) ? (short)0x3F80 : (short)0;
#pragma unroll
        for (int j = 0; j < 8; ++j) vones[j] = o1;
    }

    float4v oacc[2][4];                  // [sg][dt] out^T rows d, col=query l16
    float4v lacc[2];
#pragma unroll
    for (int sg = 0; sg < 2; ++sg) {
        lacc[sg] = (float4v){0.f, 0.f, 0.f, 0.f};
#pragma unroll
        for (int dt = 0; dt < 4; ++dt) oacc[sg][dt] = (float4v){0.f, 0.f, 0.f, 0.f};
    }

    // staging: 4 waves of a kgroup cooperate on K 64x64 and V 64x64.
    // LDS[row][chunk c] holds global chunk c ^ (row&7)  (row&7 == lane>>3).
    const int rr  = qg * 8 + (lane >> 3);
    const int sw8 = ((lane & 7) ^ (lane >> 3)) * 8;
    auto stage = [&](int ic, int buf) {
        const int m0 = ic * 64;
#pragma unroll
        for (int r = 0; r < 2; ++r) {
            gld_lds16(kbase + (size_t)(m0 + r * 32 + rr) * HDM + sw8,
                      &kts[kg][buf][r * 32 + qg * 8][0]);
            gld_lds16(vbase + (size_t)(r * 32 + rr) * LL + m0 + sw8,
                      &vts[kg][buf][r * 32 + qg * 8][0]);
        }
    };

    stage(kg, 0);   // kgroup kg handles chunks 2*i + kg, i = 0..15

    for (int i = 0; i < 16; ++i) {
        const int cur = i & 1;
        __syncthreads();   // drains vmcnt -> chunk staged; prev reads done

        if (i < 15) stage(2 * (i + 1) + kg, 1 - cur);

        // S^T = K.Q^T: rows = keys (quad*4+r), col = query (l16), per sg
        float4v s[2][4];
#pragma unroll
        for (int mt = 0; mt < 4; ++mt) {
            short8v b0 = *(const short8v*)&kts[kg][cur][mt * 16 + l16][((quad) ^ e7) * 8];
            short8v b1 = *(const short8v*)&kts[kg][cur][mt * 16 + l16][((quad + 4) ^ e7) * 8];
#pragma unroll
            for (int sg = 0; sg < 2; ++sg) {
                float4v t = (float4v){0.f, 0.f, 0.f, 0.f};
                t = __builtin_amdgcn_mfma_f32_16x16x32_bf16(b0, qfrag[sg][0], t, 0, 0, 0);
                t = __builtin_amdgcn_mfma_f32_16x16x32_bf16(b1, qfrag[sg][1], t, 0, 0, 0);
                s[sg][mt] = t;
            }
        }

        // P^T = exp2(S^T) packed to bf16 dwords, fully in registers
        unsigned pk[2][4][2];
#pragma unroll
        for (int sg = 0; sg < 2; ++sg)
#pragma unroll
            for (int mt = 0; mt < 4; ++mt) {
                float p0 = __builtin_amdgcn_exp2f(s[sg][mt][0]);
                float p1 = __builtin_amdgcn_exp2f(s[sg][mt][1]);
                float p2 = __builtin_amdgcn_exp2f(s[sg][mt][2]);
                float p3 = __builtin_amdgcn_exp2f(s[sg][mt][3]);
                pk[sg][mt][0] = (unsigned)f2u(p0) | ((unsigned)f2u(p1) << 16);
                pk[sg][mt][1] = (unsigned)f2u(p2) | ((unsigned)f2u(p3) << 16);
            }

        // 2 PV K=32 blocks per 64-key chunk; each V A-frag read feeds 2 sg
#pragma unroll
        for (int mu = 0; mu < 2; ++mu) {
            short8v pb[2];
#pragma unroll
            for (int sg = 0; sg < 2; ++sg) {
                union { short8v v8; unsigned u[4]; } U;
                U.u[0] = pk[sg][2 * mu][0];
                U.u[1] = pk[sg][2 * mu][1];
                U.u[2] = pk[sg][2 * mu + 1][0];
                U.u[3] = pk[sg][2 * mu + 1][1];
                pb[sg] = U.v8;
                lacc[sg] = __builtin_amdgcn_mfma_f32_16x16x32_bf16(vones, pb[sg], lacc[sg], 0, 0, 0);
            }
#pragma unroll
            for (int dt = 0; dt < 4; ++dt) {
                short8v va = *(const short8v*)&vts[kg][cur][dt * 16 + l16][((mu * 4 + quad) ^ e7) * 8];
#pragma unroll
                for (int sg = 0; sg < 2; ++sg)
                    oacc[sg][dt] = __builtin_amdgcn_mfma_f32_16x16x32_bf16(va, pb[sg], oacc[sg][dt], 0, 0, 0);
            }
        }
    }

    // split-K combine: static softmax => oacc/denoms add directly
    float dnm[2];
#pragma unroll
    for (int sg = 0; sg < 2; ++sg) dnm[sg] = __shfl(lacc[sg][0], l16);

    __syncthreads();   // all tile reads done; alias pool as exchange
    float* xch = (float*)smem;           // [uw 4][34][64] f32 = 34,816 B
    if (kg == 1) {
#pragma unroll
        for (int sg = 0; sg < 2; ++sg) {
#pragma unroll
            for (int dt = 0; dt < 4; ++dt)
#pragma unroll
                for (int r = 0; r < 4; ++r)
                    xch[((qg * 34 + (sg * 16 + dt * 4 + r)) << 6) + lane] = oacc[sg][dt][r];
            xch[((qg * 34 + 32 + sg) << 6) + lane] = dnm[sg];
        }
    }
    __syncthreads();
    if (kg == 0) {
        u16* ob = newv + (size_t)b * LL * 512 + h * 64;
#pragma unroll
        for (int sg = 0; sg < 2; ++sg) {
            float dt2 = dnm[sg] + xch[((qg * 34 + 32 + sg) << 6) + lane];
            float inv = 1.f / dt2;
            const size_t orow = (size_t)(q0 + sg * 16 + l16) * 512 + quad * 4;
#pragma unroll
            for (int dt = 0; dt < 4; ++dt) {
                float o0 = oacc[sg][dt][0] + xch[((qg * 34 + (sg * 16 + dt * 4 + 0)) << 6) + lane];
                float o1 = oacc[sg][dt][1] + xch[((qg * 34 + (sg * 16 + dt * 4 + 1)) << 6) + lane];
                float o2 = oacc[sg][dt][2] + xch[((qg * 34 + (sg * 16 + dt * 4 + 2)) << 6) + lane];
                float o3 = oacc[sg][dt][3] + xch[((qg * 34 + (sg * 16 + dt * 4 + 3)) << 6) + lane];
                unsigned lo = (unsigned)f2u(o0 * inv) | ((unsigned)f2u(o1 * inv) << 16);
                unsigned hi = (unsigned)f2u(o2 * inv) | ((unsigned)f2u(o3 * inv) << 16);
                uint2 val; val.x = lo; val.y = hi;
                *(uint2*)(ob + orow + dt * 16) = val;
            }
        }
    }
}

// -------------------------------------------------------------------------
// Kernel 3: MFMA FC + swish + residual + layernorm, fused — 512 threads
// (8 waves, 64 cols each => 2 waves/SIMD vs 1 before). The block's 16
// newv rows are staged ONCE into LDS via global_load_lds (linear dest +
// inverse-XOR source, XOR on read => <=2-way banks) so the 8 waves don't
// re-read A from global. MFMA per-accumulator order unchanged.
// -------------------------------------------------------------------------
__global__ __launch_bounds__(512) void fc_ln_mfma_kernel(
    const u16* __restrict__ newv,    // [4096][512] bf16
    const u16* __restrict__ fcw,     // [512][512] bf16
    const u16* __restrict__ fcb,     // [512]
    const u16* __restrict__ xp,      // [B][2050][512] padded bf16
    const u16* __restrict__ xraw,    // raw x input (dtype detect)
    void* __restrict__ out)          // bf16 or f32 per flag
{
    const int flag = detect_flag(xraw);
    const int l0 = blockIdx.x * 16;
    const int tid  = threadIdx.x;
    const int wave = tid >> 6;           // 0..7
    const int lane = tid & 63;
    const int quad = lane >> 4;
    const int l16  = lane & 15;
    const int col0 = wave * 64;

    const int bb_ = l0 >> 11;   // batch (16-row tiles never straddle)
    const size_t xbase = ((size_t)(bb_ * 2050 + (l0 & 2047) + 1)) * 512;

    __shared__ u16 As[16][512];          // 16 KB staged newv rows
    __shared__ float psum[8][16], psq[8][16];

    // stage: wave w stages rows w and w+8 (64 x 16B chunks per row).
    // LDS chunk c of row holds global chunk c ^ (row&7).
#pragma unroll
    for (int r = 0; r < 2; ++r) {
        const int row = wave + r * 8;
        gld_lds16(newv + (size_t)(l0 + row) * 512 + ((lane ^ (row & 7)) * 8),
                  &As[row][0]);
    }
    __syncthreads();   // drains vmcnt

    // aF[kc] = rows l16, cols kc*32 + quad*8 (chunk p = kc*4+quad, XOR'd)
    short8v aF[16];
#pragma unroll
    for (int kc = 0; kc < 16; ++kc)
        aF[kc] = *(const short8v*)&As[l16][(((kc * 4 + quad)) ^ (l16 & 7)) * 8];

    float4v acc[4];
#pragma unroll
    for (int nt = 0; nt < 4; ++nt) acc[nt] = (float4v){0.f, 0.f, 0.f, 0.f};

#pragma unroll
    for (int nt = 0; nt < 4; ++nt) {
        const u16* brow = fcw + (size_t)(col0 + nt * 16 + l16) * 512 + quad * 8;
#pragma unroll
        for (int kc = 0; kc < 16; ++kc) {
            short8v bF = *(const short8v*)(brow + kc * 32);
            acc[nt] = __builtin_amdgcn_mfma_f32_16x16x32_bf16(aF[kc], bF, acc[nt], 0, 0, 0);
        }
    }

    float z[4][4];
    float rs[4] = {0.f, 0.f, 0.f, 0.f}, rq[4] = {0.f, 0.f, 0.f, 0.f};
#pragma unroll
    for (int nt = 0; nt < 4; ++nt) {
        int col = col0 + nt * 16 + l16;
        float bb = b2f(fcb[col]);
#pragma unroll
        for (int r = 0; r < 4; ++r) {
            int row = quad * 4 + r;
            float y = acc[nt][r] + bb;
            float sw = y / (1.f + __expf(-y));    // swish
            float xv = b2f(xp[xbase + (size_t)row * 512 + col]);
            float zz = xv * 2.f + sw;
            z[nt][r] = zz;
            rs[r] += zz;
            rq[r] += zz * zz;
        }
    }
#pragma unroll
    for (int msk = 1; msk <= 8; msk <<= 1)
#pragma unroll
        for (int r = 0; r < 4; ++r) {
            rs[r] += __shfl_xor(rs[r], msk);
            rq[r] += __shfl_xor(rq[r], msk);
        }
    if (l16 == 0) {
#pragma unroll
        for (int r = 0; r < 4; ++r) {
            psum[wave][quad * 4 + r] = rs[r];
            psq[wave][quad * 4 + r]  = rq[r];
        }
    }
    __syncthreads();

    float mu[4], inv[4];
#pragma unroll
    for (int r = 0; r < 4; ++r) {
        int row = quad * 4 + r;
        float s = 0.f, q = 0.f;
#pragma unroll
        for (int w = 0; w < 8; ++w) { s += psum[w][row]; q += psq[w][row]; }
        float m = s * (1.f / 512.f);
        float var = q * (1.f / 512.f) - m * m;
        mu[r] = m;
        inv[r] = rsqrtf(var + 1e-5f);
    }

#pragma unroll
    for (int nt = 0; nt < 4; ++nt) {
        int col = col0 + nt * 16 + l16;
#pragma unroll
        for (int r = 0; r < 4; ++r) {
            int row = quad * 4 + r;
            float val = (z[nt][r] - mu[r]) * inv[r];
            if (flag) ((float*)out)[(size_t)(l0 + row) * 512 + col] = val;
            else      ((u16*)out)[(size_t)(l0 + row) * 512 + col] = f2u(val);
        }
    }
}

extern "C" void kernel_launch(void* const* d_in, const int* in_sizes, int n_in,
                              void* d_out, int out_size, void* d_ws, size_t ws_size,
                              hipStream_t stream) {
    (void)in_sizes; (void)n_in; (void)out_size; (void)ws_size;

    char* ws = (char*)d_ws;
    u16* xp   = (u16*)(ws + 256);        // [2][2050][512] 4,198,400 B -> ends 4,198,656
    u16* wtc  = (u16*)(ws + 4198656);    // [1536][1536] 4,718,592 B  -> ends 8,917,248
    u16* bc   = (u16*)(ws + 8917248);    // 3,072 B  -> ends 8,920,320
    u16* fwc  = (u16*)(ws + 8920320);    // 524,288 B -> ends 9,444,608
    u16* fbc  = (u16*)(ws + 9444608);    // 1,024 B  -> ends 9,445,632
    u16* qkb  = (u16*)(ws + 9445632);    // [16][2][2048][64] = 8 MB -> ends 17,834,240
    u16* vb   = (u16*)(ws + 17834240);   // [16][64][2048]    = 4 MB -> ends 22,028,544
    u16* nvc  = (u16*)(ws + 22028544);   // [2][2048][512]    = 4 MB -> ends 26,222,848

    // unified prep: 1024 (xpad) + 192 (convw via LDS) + 129 (small) = 1345
    prep_kernel<<<dim3(1345), dim3(256), 0, stream>>>(
        d_in[0], d_in[1], d_in[2], d_in[3], d_in[4],
        xp, wtc, bc, fwc, fbc);

    conv_mfma_kernel<<<dim3(32 * 12), dim3(256), 0, stream>>>(xp, wtc, bc, qkb, vb);
    attn_mfma_kernel<<<dim3(256), dim3(512), 0, stream>>>(qkb, vb, nvc);
    fc_ln_mfma_kernel<<<dim3(256), dim3(512), 0, stream>>>(
        nvc, fwc, fbc, xp, (const u16*)d_in[0], d_out);
}